// Round 19
// baseline (3514.987 us; speedup 1.0000x reference)
//
#include <hip/hip_runtime.h>
#include <hip/hip_bf16.h>

#define DIMS 1024
#define SEQ 512
#define BATCH 128
#define VOCAB 32000
#define GRID 256

typedef __attribute__((ext_vector_type(8))) short short8;
typedef __attribute__((ext_vector_type(16))) float f32x16;

__device__ __forceinline__ ushort f2bf(float x) {
    union { float f; unsigned u; } v; v.f = x;
    unsigned u = v.u;
    return (ushort)((u + 0x7FFFu + ((u >> 16) & 1u)) >> 16);
}

__global__ void conv_emb_kernel(const float* __restrict__ in, ushort* __restrict__ out, int n) {
    int idx = blockIdx.x * blockDim.x + threadIdx.x;
    int stride = gridDim.x * blockDim.x;
    for (int i = idx * 4; i < n; i += stride * 4) {
        float4 v = *(const float4*)(in + i);
        ushort4 o;
        o.x = f2bf(v.x); o.y = f2bf(v.y); o.z = f2bf(v.z); o.w = f2bf(v.w);
        *(ushort4*)(out + i) = o;
    }
}

// Persistent LSTM, fence-free flag sync, 32x32x16 MFMA core (R18 structure).
// ONE change vs R18: Bl stored k-chunk-major so each B-fragment wave-read is
// CONTIGUOUS 1KB (lane (hi,cl) reads (2ks+hi)*512 + cl*16): the canonical
// conflict-free LDS pattern. R18's column-strided reads (4KB stride, XOR in
// bits 4-6 only) had a structural 4-way bank conflict (1.52e8 counter ->
// ~1160 cyc/CU/step). No XOR swizzle needed; address bits are disjoint ORs.
// 8 waves = 2 row-halves x 4 K-quarters; load schedule = R14's proven one.
__launch_bounds__(512, 2)
__global__ void lstm_kernel(const int* __restrict__ feats,
                            const ushort* __restrict__ emb,
                            const float* __restrict__ Wf, const float* __restrict__ Uf, const float* __restrict__ bfp,
                            const float* __restrict__ Wi, const float* __restrict__ Ui, const float* __restrict__ bip,
                            const float* __restrict__ Wo, const float* __restrict__ Uo, const float* __restrict__ bop,
                            const float* __restrict__ Wc, const float* __restrict__ Uc, const float* __restrict__ bcp,
                            ushort* __restrict__ hbuf, float* __restrict__ out, int* __restrict__ flags) {
    __shared__ ushort Bl[32 * 2048];        // 131072 B, k-chunk-major: (k>>3)*512 + cl*16 + (k&7)*2
    __shared__ float pre0[64 * 36];         // partial preacts, kq{0,2}
    __shared__ float pre1[64 * 36];         // partial preacts, kq{1,3}

    const int tid = threadIdx.x;
    const int bid = blockIdx.x;
    const int rg = bid >> 7;      // row group: rows rg*64 .. rg*64+63
    const int cb = bid & 127;     // d-chunk: d = cb*8 .. cb*8+7

    // ---- one-time: load B slice (f32 -> bf16) into LDS, k-chunk-major ----
    for (int idx = tid; idx < 32 * 2048; idx += 512) {
        int cl2 = idx & 31;
        int k  = idx >> 5;
        int g  = cl2 >> 3, dd0 = cl2 & 7;
        int dw = cb * 8 + dd0;
        const float* Wg = (g == 0) ? Wf : (g == 1) ? Wi : (g == 2) ? Wo : Wc;
        const float* Ug = (g == 0) ? Uf : (g == 1) ? Ui : (g == 2) ? Uo : Uc;
        float v = (k < 1024) ? Wg[k * 1024 + dw] : Ug[(k - 1024) * 1024 + dw];
        int boff = ((k >> 3) << 9) | (cl2 << 4) | ((k & 7) << 1);
        *(ushort*)((char*)Bl + boff) = f2bf(v);
    }

    const int lane = tid & 63;
    const int w  = tid >> 6;                 // wave 0..7
    const int rh = w & 1;                    // row half: 32-row output tile
    const int kq = w >> 1;                   // K-quarter: 256k per leg
    const int cl = lane & 31;                // A row-in-tile / B col
    const int hi = lane >> 5;                // k-subgroup (0/1) within K=16
    const int lrow = rh * 32 + cl;           // local row 0..63
    const int brow = rg * 64 + lrow;         // global batch row

    const int bbase = cl << 4;               // B byte base within a 512B k-chunk
    const int kxb = kq * 256;                // x k-base for this wave

    float* myPre = (kq & 1) ? pre1 : pre0;   // target partial buffer
    // gate-phase mapping: 1 state per thread: row = tid>>3, dd = tid&7
    const int grow_ = tid >> 3;
    const int gdd   = tid & 7;
    const int gd    = cb * 8 + gdd;
    const float bF = bfp[gd], bI = bip[gd], bO = bop[gd], bC = bcp[gd];

    float cst = 0.f;
    int* myflags = flags + rg * 128;
    int fidx = feats[brow * SEQ];

    __syncthreads();   // Bl ready

    for (int t = 0; t < SEQ; t++) {
        f32x16 ac0, ac1;
        #pragma unroll
        for (int i = 0; i < 16; i++) { ac0[i] = 0.f; ac1[i] = 0.f; }

        const ushort* xrow = emb + (size_t)fidx * DIMS;
        fidx = (t + 1 < SEQ) ? feats[brow * SEQ + t + 1] : 0;

        // ---- x-leg ks 0..7 (plain loads, compiler-pipelined; covers flag hop) ----
        #pragma unroll
        for (int ks = 0; ks < 8; ks++) {
            int k = kxb + ks * 16 + hi * 8;
            short8 a = *(const short8*)(xrow + k);
            short8 b = *(const short8*)((const char*)Bl + (((k >> 3) << 9) | bbase));
            if (ks & 1) ac1 = __builtin_amdgcn_mfma_f32_32x32x16_bf16(a, b, ac1, 0, 0, 0);
            else        ac0 = __builtin_amdgcn_mfma_f32_32x32x16_bf16(a, b, ac0, 0, 0, 0);
        }

        // ---- poll my K-quarter's 32 producers + asm-batch 16 h-loads ----
        short8 hv[16];
        if (t > 0) {
            long guard = 0;
            for (;;) {
                int f0 = __hip_atomic_load(myflags + kq * 32 + cl, __ATOMIC_RELAXED, __HIP_MEMORY_SCOPE_AGENT);
                if (__all(f0 >= t)) break;
                __builtin_amdgcn_s_sleep(1);
                if (++guard > 100000000L) break;  // deadlock safety valve
            }
            const ushort* hbase = hbuf + (size_t)((t & 1) * 2 + rg) * (128 * 512);
            #pragma unroll
            for (int ks = 0; ks < 16; ks++) {
                int chunk = kq * 32 + ks * 2 + hi;
                const ushort* hp = hbase + (chunk << 9) + lrow * 8;
                asm volatile("global_load_dwordx4 %0, %1, off sc0 sc1"
                             : "=v"(hv[ks]) : "v"(hp) : "memory");
            }
        }

        // ---- x-leg ks 8..15 (hides h-load flight) ----
        #pragma unroll
        for (int ks = 8; ks < 16; ks++) {
            int k = kxb + ks * 16 + hi * 8;
            short8 a = *(const short8*)(xrow + k);
            short8 b = *(const short8*)((const char*)Bl + (((k >> 3) << 9) | bbase));
            if (ks & 1) ac1 = __builtin_amdgcn_mfma_f32_32x32x16_bf16(a, b, ac1, 0, 0, 0);
            else        ac0 = __builtin_amdgcn_mfma_f32_32x32x16_bf16(a, b, ac0, 0, 0, 0);
        }

        // ---- h-leg: wait once, then registers + LDS only ----
        if (t > 0) {
            asm volatile("s_waitcnt vmcnt(0)" ::: "memory");
            __builtin_amdgcn_sched_barrier(0);   // rule #18
            #pragma unroll
            for (int ks = 0; ks < 16; ks++) {
                int k = 1024 + kxb + ks * 16 + hi * 8;
                short8 b = *(const short8*)((const char*)Bl + (((k >> 3) << 9) | bbase));
                if (ks & 1) ac1 = __builtin_amdgcn_mfma_f32_32x32x16_bf16(hv[ks], b, ac1, 0, 0, 0);
                else        ac0 = __builtin_amdgcn_mfma_f32_32x32x16_bf16(hv[ks], b, ac0, 0, 0, 0);
            }
        }

        // ---- two-phase partial reduction in LDS ----
        // C/D map (m74/m101): col = lane&31, row = (reg&3) + 8*(reg>>2) + 4*(lane>>5)
        if (kq < 2) {
            #pragma unroll
            for (int r = 0; r < 16; r++) {
                int row = (r & 3) + 8 * (r >> 2) + 4 * hi + rh * 32;
                myPre[row * 36 + cl] = ac0[r] + ac1[r];
            }
        }
        __syncthreads();   // phase A partials in place
        if (kq >= 2) {
            #pragma unroll
            for (int r = 0; r < 16; r++) {
                int row = (r & 3) + 8 * (r >> 2) + 4 * hi + rh * 32;
                myPre[row * 36 + cl] += ac0[r] + ac1[r];
            }
        }
        __syncthreads();   // sync A: pre0 + pre1 complete

        // ---- gates: 1 state per thread ----
        {
            int base = grow_ * 36;
            float pf = pre0[base + gdd]      + pre1[base + gdd]      + bF;
            float pi = pre0[base + 8 + gdd]  + pre1[base + 8 + gdd]  + bI;
            float po = pre0[base + 16 + gdd] + pre1[base + 16 + gdd] + bO;
            float pc = pre0[base + 24 + gdd] + pre1[base + 24 + gdd] + bC;
            float f  = 1.f / (1.f + __expf(-pf));
            float ig = 1.f / (1.f + __expf(-pi));
            float o  = 1.f / (1.f + __expf(-po));
            float e2 = __expf(2.f * pc);
            float cc = (e2 - 1.f) / (e2 + 1.f);
            float cn = f * cst + ig * cc;
            cst = cn;
            float e2c = __expf(2.f * cn);
            float th  = (e2c - 1.f) / (e2c + 1.f);
            float h   = o * th;
            if (t < SEQ - 1) {
                // coalesced publish: thread tid -> hnext[cb*512 + tid]
                ushort* hw = hbuf + (size_t)(((t + 1) & 1) * 2 + rg) * (128 * 512) + cb * 512 + tid;
                __hip_atomic_store(hw, f2bf(h), __ATOMIC_RELAXED, __HIP_MEMORY_SCOPE_AGENT);
            } else {
                int gr = rg * 64 + grow_;
                out[gr * 2048 + gd] = h;
                out[gr * 2048 + 1024 + gd] = cn;
            }
        }

        if (t < SEQ - 1) {
            asm volatile("s_waitcnt vmcnt(0)" ::: "memory");  // h stores acked at coherence point
            __syncthreads();                                   // sync B: publishes done; pre[] reusable
            if (tid == 0) {
                __hip_atomic_store(myflags + cb, t + 1, __ATOMIC_RELAXED, __HIP_MEMORY_SCOPE_AGENT);
            }
        }
    }
}

extern "C" void kernel_launch(void* const* d_in, const int* in_sizes, int n_in,
                              void* d_out, int out_size, void* d_ws, size_t ws_size,
                              hipStream_t stream) {
    const int*   feats = (const int*)d_in[0];
    const float* emb_f = (const float*)d_in[1];
    const float* Wf = (const float*)d_in[2];
    const float* Uf = (const float*)d_in[3];
    const float* bf_ = (const float*)d_in[4];
    const float* Wi = (const float*)d_in[5];
    const float* Ui = (const float*)d_in[6];
    const float* bi_ = (const float*)d_in[7];
    const float* Wo = (const float*)d_in[8];
    const float* Uo = (const float*)d_in[9];
    const float* bo_ = (const float*)d_in[10];
    const float* Wc = (const float*)d_in[11];
    const float* Uc = (const float*)d_in[12];
    const float* bc_ = (const float*)d_in[13];

    char* ws = (char*)d_ws;
    ushort* emb_bf = (ushort*)ws;                          // 65,536,000 B
    ushort* hbuf   = (ushort*)(ws + 65536000);             // 2x2x128x64x8 bf16 = 524,288 B
    int*    flags  = (int*)(ws + 65536000 + 524288);       // 256 flags

    hipMemsetAsync(flags, 0, 1024, stream);
    conv_emb_kernel<<<1024, 256, 0, stream>>>(emb_f, emb_bf, VOCAB * DIMS);
    lstm_kernel<<<GRID, 512, 0, stream>>>(feats, emb_bf,
                                          Wf, Uf, bf_, Wi, Ui, bi_,
                                          Wo, Uo, bo_, Wc, Uc, bc_,
                                          hbuf, (float*)d_out, flags);
}